// Round 12
// baseline (2257.121 us; speedup 1.0000x reference)
//
#include <hip/hip_runtime.h>
#include <math.h>

// Problem constants (B=1, NHEADS=1)
#define TT   3
#define CC   64
#define HH   192
#define WW   192
#define HWW  (HH*WW)       // 36864
#define NHC  24            // H / STRIDE0_A
#define NWC  24
#define QC   1728          // T*NHC*NWC
#define SC   192           // st*WS*WS = 3*8*8
#define NPIX 49            // PS*PS
#define KK   7
#define NHF  48            // H / STRIDE0
#define NWF  48
#define QF   6912          // T*NHF*NWF

__device__ __forceinline__ int reflect(int i, int L) {
  i = i < 0 ? -i : i;
  return (i >= L) ? (2 * (L - 1) - i) : i;
}

// ---------------------------------------------------------------------------
// (T,C,H,W) -> (T,H,W,C) fp32 transpose, 64x64 (c,x) tiles per (t,y).
// ---------------------------------------------------------------------------
__global__ void transpose_tchw_thwc(const float* __restrict__ in0,
                                    const float* __restrict__ in1,
                                    float* __restrict__ out0,
                                    float* __restrict__ out1) {
  const float* in = blockIdx.y ? in1 : in0;
  float* out = blockIdx.y ? out1 : out0;
  int b = blockIdx.x;              // 0 .. T*H*(W/64)-1
  int x0 = (b % 3) * 64;
  int ty = b / 3;                  // t*H + y
  int t = ty / HH, y = ty % HH;

  __shared__ float tile[64][65];   // +1 pad
  int lx = threadIdx.x & 63;
  int lc = threadIdx.x >> 6;       // 0..3

  const float* src = in + (size_t)t * CC * HWW + (size_t)y * WW + x0;
#pragma unroll
  for (int i = 0; i < 16; ++i) {
    int c = lc + i * 4;
    tile[c][lx] = src[(size_t)c * HWW + lx];
  }
  __syncthreads();
  float* dst = out + ((size_t)(t * HH + y) * WW + x0) * CC;
#pragma unroll
  for (int i = 0; i < 16; ++i) {
    int x = lc + i * 4;
    dst[(size_t)x * CC + lx] = tile[lx][x];   // coalesced along c
  }
}

// ---------------------------------------------------------------------------
// Coarse dists + fused top-k, bit-exact vs the XLA chain:
//   w(s,p) = serial ascending-c FMA chain, single fp32 acc (c 0..63, carried
//            in a register across the four c-quarters).
//   dist  = 49 sequential fp32 adds, p ascending (lax.scan order).
//   top-k = wave-parallel selection, bit-exact vs serial strict-'>'
//           ascending scan (value tie -> lower index).
//
// v13 = v11 (async-stage split, 148us champion) + S-PAIR, isolated at last:
//  - v12 post-mortem: scalar-q failed (loads stayed vector, +90MB fetch,
//    33MB spill). qbuf broadcast must stay in LDS; the halvable term is the
//    READ COUNT: one qbuf read feeding TWO dots.
//  - Lane owns sA=lane&31 and sB=sA+32. rres = w + 4*(lane>>5); p=rres+8i,
//    i=0..6. qbuf reads/block 2496 -> 1344 (-46%); region +8% (uniform
//    step-6 duplicate of p=48 where rres!=0). Net LDS inst -19%.
//  - Spill engineering: compute is LANE-UNIFORM (no divergent guard around
//    the unrolled body = no v7 unroll-bail/demotion); only the wbuf store
//    is predicated (v4-proven). Arrays acc/pxb fully unrolled (v11-proven).
//  - Region slot-evenness preserved: 8 lanes/16B-slot for bA and bB
//    (bB = bA + 896B, 896 % 128 == 0). qbuf read = 2-address (free, m136).
// ---------------------------------------------------------------------------
__global__ __launch_bounds__(256, 4) void coarse_fma_kernel(
    const float* __restrict__ v0, const float* __restrict__ v1,
    int* __restrict__ topk) {
  int bid = blockIdx.x;
  int q = (bid & 7) * (QC / 8) + (bid >> 3);   // XCD swizzle, bijective
  int qt = q / (NHC * NWC);
  int r = q % (NHC * NWC);
  int qh = (r / NWC) * 8;
  int qw = (r % NWC) * 8;

  __shared__ float4 region4[4 * 196];   // [c4h][px] 12544 B; wbuf aliases
  __shared__ float4 qbuf4[16 * 49];     // [c4][p]   12544 B
  __shared__ float  dall[SC];           // per-block dists, 768 B
  float* wbuf = (float*)region4;        // [s][p] 12544 B, after compute sync

  int tid = threadIdx.x;
  int lane = tid & 63;
  int w = tid >> 6;                     // wave id 0..3
  int hf = lane >> 5;                   // half-wave selector
  int sA = lane & 31;                   // owns sA and sA+32
  int oiA = sA >> 3, oj = sA & 7;
  int rres = w + 4 * hf;                // p residue mod 8, 0..7
  // p = rres + 8*i, i=0..6; step 6 real only when rres==0 (p=48).

  // Per-lane region byte offsets (for sA; sB = +896B). p clamped to 48 for
  // the duplicate step (computed, never stored).
  int pxb[7], pq[7];
#pragma unroll
  for (int i = 0; i < 7; ++i) {
    int p = rres + 8 * i;
    if (p > 48) p = 48;
    pq[i] = p;
    pxb[i] = ((oiA + p / 7) * 14 + (oj + p % 7)) * 16;
  }

  // Stage query patch [c4][p] float4 (write chunk-slots even over lanes).
  {
    const float* b0 = v0 + (size_t)qt * HWW * CC;
    for (int idx = tid; idx < 896; idx += 256) {
      int p = (idx & 7) | ((idx >> 7) << 3);
      int c4 = (idx >> 3) & 15;
      if (p < 49) {
        int ry = reflect(qh + p / 7 - 3, HH);
        int rx = reflect(qw + p % 7 - 3, WW);
        qbuf4[c4 * 49 + p] = *reinterpret_cast<const float4*>(
            b0 + ((size_t)ry * WW + rx) * CC + c4 * 4);
      }
    }
  }

  // Staging: slot j <-> idx = tid + 256*j; valid iff px<196. Invalid-slot
  // addresses are reflect-clamped in-bounds -> loads UNCONDITIONAL; only
  // the LDS store is predicated (v11's proven no-spill pattern).
  float4 rr0, rr1, rr2, rr3;
  int src0, src1, src2, src3;
#define SLOT_SRC(j, srcv)                                                   \
  {                                                                         \
    int idx = tid + 256 * (j);                                              \
    int px = (idx & 7) | ((idx >> 5) << 3);                                 \
    int c4h = (idx >> 3) & 3;                                               \
    int ry = reflect(qh - 7 + px / 14, HH);                                 \
    int rx = reflect(qw - 7 + px % 14, WW);                                 \
    srcv = (ry * WW + rx) * CC + c4h * 4;  /* float idx; +ph*16 via base */ \
  }
  SLOT_SRC(0, src0) SLOT_SRC(1, src1) SLOT_SRC(2, src2) SLOT_SRC(3, src3)
#undef SLOT_SRC

#define ISSUE(nb)                                                           \
  {                                                                         \
    rr0 = *reinterpret_cast<const float4*>((nb) + src0);                    \
    rr1 = *reinterpret_cast<const float4*>((nb) + src1);                    \
    rr2 = *reinterpret_cast<const float4*>((nb) + src2);                    \
    rr3 = *reinterpret_cast<const float4*>((nb) + src3);                    \
  }
#define WRITE_SLOT(j, rrv)                                                  \
  {                                                                         \
    int idx = tid + 256 * (j);                                              \
    int px = (idx & 7) | ((idx >> 5) << 3);                                 \
    int c4h = (idx >> 3) & 3;                                               \
    if (px < 196) region4[c4h * 196 + px] = rrv;                            \
  }
#define WRITE_ALL                                                           \
  WRITE_SLOT(0, rr0) WRITE_SLOT(1, rr1) WRITE_SLOT(2, rr2) WRITE_SLOT(3, rr3)

  // Prologue: issue (ct=0, ph=0) staging loads.
  ISSUE(v1)

  for (int ct = 0; ct < 3; ++ct) {
    const float* b1 = v1 + (size_t)ct * HWW * CC;
    float accA[7], accB[7];
#pragma unroll
    for (int i = 0; i < 7; ++i) { accA[i] = 0.f; accB[i] = 0.f; }

#pragma unroll
    for (int ph = 0; ph < 4; ++ph) {
      __syncthreads();  // prior region4/wbuf readers done; drains rr loads
      WRITE_ALL         // commit phase ph (data already resident)
      __syncthreads();  // region4 visible
      // Issue next phase's loads; they complete under COMPUTE below.
      const float* nb = (ph < 3) ? (b1 + (ph + 1) * 16)
                                 : ((ct < 2) ? (b1 + (size_t)HWW * CC) : b1);
      ISSUE(nb)

      // Continue each dot's serial chain: c = 16*ph .. 16*ph+15, ascending,
      // single register accumulator per (s,p) — bit-identical ordering.
      // One qbuf read feeds BOTH sA and sB dots. All lanes run all 7 steps
      // (uniform; step 6 duplicates p=48 where rres!=0, never stored).
#pragma unroll
      for (int i = 0; i < 7; ++i) {
        const char* rbase = reinterpret_cast<const char*>(region4) + pxb[i];
#pragma unroll
        for (int c4h = 0; c4h < 4; ++c4h) {
          float4 a = qbuf4[(ph * 4 + c4h) * 49 + pq[i]];
          float4 bA = *reinterpret_cast<const float4*>(rbase + c4h * 3136);
          float4 bB =
              *reinterpret_cast<const float4*>(rbase + c4h * 3136 + 896);
          accA[i] = fmaf(a.x, bA.x, accA[i]);   // ascending c, fused
          accA[i] = fmaf(a.y, bA.y, accA[i]);
          accA[i] = fmaf(a.z, bA.z, accA[i]);
          accA[i] = fmaf(a.w, bA.w, accA[i]);
          accB[i] = fmaf(a.x, bB.x, accB[i]);
          accB[i] = fmaf(a.y, bB.y, accB[i]);
          accB[i] = fmaf(a.z, bB.z, accB[i]);
          accB[i] = fmaf(a.w, bB.w, accB[i]);
        }
      }
    }

    __syncthreads();     // all region4 readers done -> wbuf alias writable
    // Publish dots; reduce over p in scan order. Predicated store only
    // (step 6 stored iff rres==0 -> p=48 <= 48).
#pragma unroll
    for (int i = 0; i < 7; ++i) {
      int p = rres + 8 * i;
      if (p <= 48) {
        wbuf[sA * 49 + p] = accA[i];
        wbuf[(sA + 32) * 49 + p] = accB[i];
      }
    }
    __syncthreads();
    if (tid < 64) {
      float a = 0.f;
      const float* wr = wbuf + tid * 49;
      for (int p = 0; p < NPIX; ++p)
        a = __fadd_rn(a, wr[p]);         // scan order, fp32
      dall[ct * 64 + tid] = a;
    }
    // Next ct's first __syncthreads fences the reduce before region reuse.
  }
#undef ISSUE
#undef WRITE_SLOT
#undef WRITE_ALL

  // Fused top-k on wave 0. Lane owns candidates {lane, lane+64, lane+128}.
  // Bit-exact vs serial strict-'>' ascending scan (ties -> lowest index).
  __syncthreads();
  if (tid < 64) {
    float va = dall[lane], vb = dall[lane + 64], vc = dall[lane + 128];
    int tk = 0;                          // taken bitmask (per-lane, 3 bits)
#pragma unroll
    for (int k = 0; k < KK; ++k) {
      float bv = -INFINITY;
      int bi = 0x7fffffff;
      if (!(tk & 1) && va > bv) { bv = va; bi = lane; }
      if (!(tk & 2) && vb > bv) { bv = vb; bi = lane + 64; }
      if (!(tk & 4) && vc > bv) { bv = vc; bi = lane + 128; }
#pragma unroll
      for (int off = 32; off > 0; off >>= 1) {
        float ov = __shfl_xor(bv, off, 64);
        int oi2 = __shfl_xor(bi, off, 64);
        if (ov > bv || (ov == bv && oi2 < bi)) { bv = ov; bi = oi2; }
      }
      if ((bi & 63) == lane) tk |= 1 << (bi >> 6);
      if (lane == 0) topk[q * KK + k] = bi;
    }
  }
}

// ---------------------------------------------------------------------------
// Refine. One block per fine query, 448 threads = 7 waves, one wave per
// candidate k. Query patch staged once in LDS; candidate loads batched
// 7-wide for ILP. XCD swizzle for L2 locality.
// ---------------------------------------------------------------------------
__global__ __launch_bounds__(448, 7) void refine_kernel(
    const float* __restrict__ v0, const float* __restrict__ v1,
    const int* __restrict__ topk, float* __restrict__ out) {
  int bid = blockIdx.x;
  int f = (bid & 7) * (QF / 8) + (bid >> 3);   // XCD swizzle, bijective
  int ft = f / (NHF * NWF);
  int r = f % (NHF * NWF);
  int fi = r / NWF, fj = r % NWF;
  int fh = fi * 4, fw = fj * 4;
  int ci = fi >> 1, cj = fj >> 1;     // clip is a no-op here
  int dh = (fi & 1) * 4, dw = (fj & 1) * 4;
  int qlin = ft * (NHC * NWC) + ci * NWC + cj;

  int tid = threadIdx.x;
  int lane = tid & 63;
  int k = tid >> 6;                   // wave id == candidate id, 0..6

  __shared__ float qs[NPIX * CC];     // [p][c], 12544 B

  {
    const float* b0 = v0 + (size_t)ft * HWW * CC;
#pragma unroll
    for (int i = 0; i < 7; ++i) {     // 7 * 448 = 3136 = NPIX*CC exactly
      int idx = tid + i * 448;
      int p = idx >> 6, c = idx & 63;
      int ry = reflect(fh + p / 7 - 3, HH);
      int rx = reflect(fw + p % 7 - 3, WW);
      qs[idx] = b0[((size_t)ry * WW + rx) * CC + c];
    }
  }
  __syncthreads();

  int it, ih, iw;
  if (k == 0) {
    it = ft; ih = fh; iw = fw;
  } else {
    int s = topk[qlin * KK + k];
    int ti = s >> 6;                  // ct index (t0 == 0 always)
    int oi = (s >> 3) & 7, oj = s & 7;
    it = ti;
    ih = reflect(ci * 8 + oi - 4 + dh, HH);
    iw = reflect(cj * 8 + oj - 4 + dw, WW);
  }

  const float* b1 = v1 + (size_t)it * HWW * CC;
  float acc = 0.f;
#pragma unroll
  for (int pr = 0; pr < 7; ++pr) {
    int ry = reflect(ih + pr - 3, HH);
    const float* rowp = b1 + (size_t)ry * WW * CC + lane;
    float vals[7];
#pragma unroll
    for (int pc = 0; pc < 7; ++pc) {
      int rx = reflect(iw + pc - 3, WW);
      vals[pc] = rowp[(size_t)rx * CC];       // 7 independent loads in flight
    }
#pragma unroll
    for (int pc = 0; pc < 7; ++pc)
      acc = fmaf(qs[(pr * 7 + pc) * CC + lane], vals[pc], acc);
  }
#pragma unroll
  for (int off = 32; off > 0; off >>= 1)
    acc += __shfl_xor(acc, off, 64);
  if (lane == 0) {
    float* dout = out;                      // [0, QF*KK)
    float* iout = out + (size_t)QF * KK;    // [QF*KK, QF*KK*4)
    dout[(size_t)f * KK + k] = acc;
    float* ip = iout + ((size_t)f * KK + k) * 3;
    ip[0] = (float)it;
    ip[1] = (float)ih;
    ip[2] = (float)iw;
  }
}

// ---------------------------------------------------------------------------
extern "C" void kernel_launch(void* const* d_in, const int* in_sizes, int n_in,
                              void* d_out, int out_size, void* d_ws,
                              size_t ws_size, hipStream_t stream) {
  const float* vid0 = (const float*)d_in[0];
  const float* vid1 = (const float*)d_in[1];
  // d_in[2] = flows: unused by the reference.
  float* out = (float*)d_out;

  // Workspace layout:
  //   topk  : QC*KK int32 = 48 KB
  //   v0t   : TT*HH*WW*CC fp32 = 28.3 MB
  //   v1t   : 28.3 MB
  char* ws = (char*)d_ws;
  int* topk = (int*)ws;
  size_t off = (size_t)QC * KK * sizeof(int);
  off = (off + 255) & ~(size_t)255;
  float* v0t = (float*)(ws + off);
  size_t vbytes = (size_t)TT * HWW * CC * sizeof(float);
  float* v1t = (float*)(ws + off + vbytes);

  transpose_tchw_thwc<<<dim3(TT * HH * (WW / 64), 2), 256, 0, stream>>>(
      vid0, vid1, v0t, v1t);
  coarse_fma_kernel<<<QC, 256, 0, stream>>>(v0t, v1t, topk);
  refine_kernel<<<QF, 448, 0, stream>>>(v0t, v1t, topk, out);
}

// Round 13
// 268.172 us; speedup vs baseline: 8.4167x; 8.4167x over previous
//
#include <hip/hip_runtime.h>
#include <math.h>

// Problem constants (B=1, NHEADS=1)
#define TT   3
#define CC   64
#define HH   192
#define WW   192
#define HWW  (HH*WW)       // 36864
#define NHC  24            // H / STRIDE0_A
#define NWC  24
#define QC   1728          // T*NHC*NWC
#define SC   192           // st*WS*WS = 3*8*8
#define NPIX 49            // PS*PS
#define KK   7
#define NHF  48            // H / STRIDE0
#define NWF  48
#define QF   6912          // T*NHF*NWF

__device__ __forceinline__ int reflect(int i, int L) {
  i = i < 0 ? -i : i;
  return (i >= L) ? (2 * (L - 1) - i) : i;
}

// ---------------------------------------------------------------------------
// (T,C,H,W) -> (T,H,W,C) fp32 transpose, 64x64 (c,x) tiles per (t,y).
// ---------------------------------------------------------------------------
__global__ void transpose_tchw_thwc(const float* __restrict__ in0,
                                    const float* __restrict__ in1,
                                    float* __restrict__ out0,
                                    float* __restrict__ out1) {
  const float* in = blockIdx.y ? in1 : in0;
  float* out = blockIdx.y ? out1 : out0;
  int b = blockIdx.x;              // 0 .. T*H*(W/64)-1
  int x0 = (b % 3) * 64;
  int ty = b / 3;                  // t*H + y
  int t = ty / HH, y = ty % HH;

  __shared__ float tile[64][65];   // +1 pad
  int lx = threadIdx.x & 63;
  int lc = threadIdx.x >> 6;       // 0..3

  const float* src = in + (size_t)t * CC * HWW + (size_t)y * WW + x0;
#pragma unroll
  for (int i = 0; i < 16; ++i) {
    int c = lc + i * 4;
    tile[c][lx] = src[(size_t)c * HWW + lx];
  }
  __syncthreads();
  float* dst = out + ((size_t)(t * HH + y) * WW + x0) * CC;
#pragma unroll
  for (int i = 0; i < 16; ++i) {
    int x = lc + i * 4;
    dst[(size_t)x * CC + lx] = tile[lx][x];   // coalesced along c
  }
}

// ---------------------------------------------------------------------------
// Coarse dists + fused top-k, bit-exact vs the XLA chain:
//   w(s,p) = serial ascending-c FMA chain, single fp32 acc (c 0..63, carried
//            in a register across the four c-quarters).
//   dist  = 49 sequential fp32 adds, p ascending (lax.scan order).
//   top-k = wave-parallel selection, bit-exact vs serial strict-'>'
//           ascending scan (value tie -> lower index).
//
// v14 = v11 VERBATIM (round-10 champion: 148us coarse, 268us total).
// Session ledger on coarse restructures beyond this point:
//  - s-pair dual-accumulator (v4/v7/v8/v9/v13): 5x catastrophic scratch
//    demotion (WRITE 0.6-5 GB) regardless of guard/array/uniformity
//    engineering -> compiler register-pressure cliff, door closed.
//  - scalar-q via readfirstlane (v12): not scalarized; +90MB FETCH. Closed.
//  - quarter-staging + 100% occupancy (v6+v7): LDS pipe ~saturated; the
//    remaining 148us-vs-~86us floor gap is barrier-latency exposure the
//    HIP compiler's vmcnt(0)-at-barrier drain makes unreachable (same
//    structural story as the guide's m97 ceiling).
// Structure: single acc[13]/thread; async-stage split (ISSUE next phase's
// 4 loads right after the visibility barrier -> ~850cy compute hides them;
// WRITE commits resident registers after the next drain). LDS 25.5 KB.
// ---------------------------------------------------------------------------
__global__ __launch_bounds__(256, 4) void coarse_fma_kernel(
    const float* __restrict__ v0, const float* __restrict__ v1,
    int* __restrict__ topk) {
  int bid = blockIdx.x;
  int q = (bid & 7) * (QC / 8) + (bid >> 3);   // XCD swizzle, bijective
  int qt = q / (NHC * NWC);
  int r = q % (NHC * NWC);
  int qh = (r / NWC) * 8;
  int qw = (r % NWC) * 8;

  __shared__ float4 region4[4 * 196];   // [c4h][px] 12544 B; wbuf aliases
  __shared__ float4 qbuf4[16 * 49];     // [c4][p]   12544 B
  __shared__ float  dall[SC];           // per-block dists, 768 B
  float* wbuf = (float*)region4;        // [s][p] 12544 B, after compute sync

  int tid = threadIdx.x;
  int s = tid & 63;
  int w = tid >> 6;                     // wave id 0..3
  int oi = s >> 3, oj = s & 7;

  // Per-thread region byte offsets, ct-independent. p = w + 4*i.
  int pxb[13];
#pragma unroll
  for (int i = 0; i < 13; ++i) {
    int p = w + 4 * i;
    if (p > 48) p = 48;                 // clamped slot is never used
    pxb[i] = ((oi + p / 7) * 14 + (oj + p % 7)) * 16;
  }

  // Stage query patch [c4][p] float4 (write chunk-slots even over lanes).
  {
    const float* b0 = v0 + (size_t)qt * HWW * CC;
    for (int idx = tid; idx < 896; idx += 256) {
      int p = (idx & 7) | ((idx >> 7) << 3);
      int c4 = (idx >> 3) & 15;
      if (p < 49) {
        int ry = reflect(qh + p / 7 - 3, HH);
        int rx = reflect(qw + p % 7 - 3, WW);
        qbuf4[c4 * 49 + p] = *reinterpret_cast<const float4*>(
            b0 + ((size_t)ry * WW + rx) * CC + c4 * 4);
      }
    }
  }

  // Staging: slot j <-> idx = tid + 256*j, bijective onto (c4h, px<256);
  // valid iff px<196. Addresses of invalid slots are reflect-clamped
  // in-bounds -> loads are UNCONDITIONAL (no conditional-def hazard);
  // only the LDS store is predicated.
  float4 rr0, rr1, rr2, rr3;
  int src0, src1, src2, src3;
#define SLOT_SRC(j, srcv)                                                   \
  {                                                                         \
    int idx = tid + 256 * (j);                                              \
    int px = (idx & 7) | ((idx >> 5) << 3);                                 \
    int c4h = (idx >> 3) & 3;                                               \
    int ry = reflect(qh - 7 + px / 14, HH);                                 \
    int rx = reflect(qw - 7 + px % 14, WW);                                 \
    srcv = (ry * WW + rx) * CC + c4h * 4;  /* float idx; +ph*16 via base */ \
  }
  SLOT_SRC(0, src0) SLOT_SRC(1, src1) SLOT_SRC(2, src2) SLOT_SRC(3, src3)
#undef SLOT_SRC

#define ISSUE(nb)                                                           \
  {                                                                         \
    rr0 = *reinterpret_cast<const float4*>((nb) + src0);                    \
    rr1 = *reinterpret_cast<const float4*>((nb) + src1);                    \
    rr2 = *reinterpret_cast<const float4*>((nb) + src2);                    \
    rr3 = *reinterpret_cast<const float4*>((nb) + src3);                    \
  }
#define WRITE_SLOT(j, rrv)                                                  \
  {                                                                         \
    int idx = tid + 256 * (j);                                              \
    int px = (idx & 7) | ((idx >> 5) << 3);                                 \
    int c4h = (idx >> 3) & 3;                                               \
    if (px < 196) region4[c4h * 196 + px] = rrv;                            \
  }
#define WRITE_ALL                                                           \
  WRITE_SLOT(0, rr0) WRITE_SLOT(1, rr1) WRITE_SLOT(2, rr2) WRITE_SLOT(3, rr3)

  // Prologue: issue (ct=0, ph=0) staging loads.
  ISSUE(v1)

  for (int ct = 0; ct < 3; ++ct) {
    const float* b1 = v1 + (size_t)ct * HWW * CC;
    float acc[13];
#pragma unroll
    for (int i = 0; i < 13; ++i) acc[i] = 0.f;

#pragma unroll
    for (int ph = 0; ph < 4; ++ph) {
      __syncthreads();  // prior region4/wbuf readers done; drains rr loads
      WRITE_ALL         // commit phase ph (data already resident)
      __syncthreads();  // region4 visible
      // Issue next phase's loads; they complete under COMPUTE below.
      // ph=3: next ct's ph0 (or a harmless dummy reload on the last ct).
      const float* nb = (ph < 3) ? (b1 + (ph + 1) * 16)
                                 : ((ct < 2) ? (b1 + (size_t)HWW * CC) : b1);
      ISSUE(nb)

      // Continue each dot's serial chain: c = 16*ph .. 16*ph+15, ascending,
      // single register accumulator per (s,p) — bit-identical ordering.
#pragma unroll
      for (int i = 0; i < 13; ++i) {
        if (i < 12 || w == 0) {          // p = w+48 exists only for wave 0
          int p = w + 4 * i;             // wave-uniform -> qbuf read = bcast
          const char* rbase = reinterpret_cast<const char*>(region4) + pxb[i];
#pragma unroll
          for (int c4h = 0; c4h < 4; ++c4h) {
            float4 a = qbuf4[(ph * 4 + c4h) * 49 + p];
            float4 b = *reinterpret_cast<const float4*>(rbase + c4h * 3136);
            acc[i] = fmaf(a.x, b.x, acc[i]);   // ascending c, fused
            acc[i] = fmaf(a.y, b.y, acc[i]);
            acc[i] = fmaf(a.z, b.z, acc[i]);
            acc[i] = fmaf(a.w, b.w, acc[i]);
          }
        }
      }
    }

    __syncthreads();     // all region4 readers done -> wbuf alias writable
    // Publish dots; reduce over p in scan order. (rr holds next ct's ph0
    // data in registers across this phase — untouched.)
#pragma unroll
    for (int i = 0; i < 13; ++i) {
      if (i < 12 || w == 0) wbuf[s * 49 + (w + 4 * i)] = acc[i];
    }
    __syncthreads();
    if (tid < 64) {
      float a = 0.f;
      const float* wr = wbuf + tid * 49;
      for (int p = 0; p < NPIX; ++p)
        a = __fadd_rn(a, wr[p]);         // scan order, fp32
      dall[ct * 64 + tid] = a;
    }
    // Next ct's first __syncthreads fences the reduce before region reuse.
  }
#undef ISSUE
#undef WRITE_SLOT
#undef WRITE_ALL

  // Fused top-k on wave 0. Lane owns candidates {lane, lane+64, lane+128}.
  // Bit-exact vs serial strict-'>' ascending scan (ties -> lowest index).
  __syncthreads();
  if (tid < 64) {
    int lane = tid;
    float va = dall[lane], vb = dall[lane + 64], vc = dall[lane + 128];
    int tk = 0;                          // taken bitmask (per-lane, 3 bits)
#pragma unroll
    for (int k = 0; k < KK; ++k) {
      float bv = -INFINITY;
      int bi = 0x7fffffff;
      if (!(tk & 1) && va > bv) { bv = va; bi = lane; }
      if (!(tk & 2) && vb > bv) { bv = vb; bi = lane + 64; }
      if (!(tk & 4) && vc > bv) { bv = vc; bi = lane + 128; }
#pragma unroll
      for (int off = 32; off > 0; off >>= 1) {
        float ov = __shfl_xor(bv, off, 64);
        int oi2 = __shfl_xor(bi, off, 64);
        if (ov > bv || (ov == bv && oi2 < bi)) { bv = ov; bi = oi2; }
      }
      if ((bi & 63) == lane) tk |= 1 << (bi >> 6);
      if (lane == 0) topk[q * KK + k] = bi;
    }
  }
}

// ---------------------------------------------------------------------------
// Refine. One block per fine query, 448 threads = 7 waves, one wave per
// candidate k. Query patch staged once in LDS; candidate loads batched
// 7-wide for ILP. XCD swizzle for L2 locality.
// ---------------------------------------------------------------------------
__global__ __launch_bounds__(448, 7) void refine_kernel(
    const float* __restrict__ v0, const float* __restrict__ v1,
    const int* __restrict__ topk, float* __restrict__ out) {
  int bid = blockIdx.x;
  int f = (bid & 7) * (QF / 8) + (bid >> 3);   // XCD swizzle, bijective
  int ft = f / (NHF * NWF);
  int r = f % (NHF * NWF);
  int fi = r / NWF, fj = r % NWF;
  int fh = fi * 4, fw = fj * 4;
  int ci = fi >> 1, cj = fj >> 1;     // clip is a no-op here
  int dh = (fi & 1) * 4, dw = (fj & 1) * 4;
  int qlin = ft * (NHC * NWC) + ci * NWC + cj;

  int tid = threadIdx.x;
  int lane = tid & 63;
  int k = tid >> 6;                   // wave id == candidate id, 0..6

  __shared__ float qs[NPIX * CC];     // [p][c], 12544 B

  {
    const float* b0 = v0 + (size_t)ft * HWW * CC;
#pragma unroll
    for (int i = 0; i < 7; ++i) {     // 7 * 448 = 3136 = NPIX*CC exactly
      int idx = tid + i * 448;
      int p = idx >> 6, c = idx & 63;
      int ry = reflect(fh + p / 7 - 3, HH);
      int rx = reflect(fw + p % 7 - 3, WW);
      qs[idx] = b0[((size_t)ry * WW + rx) * CC + c];
    }
  }
  __syncthreads();

  int it, ih, iw;
  if (k == 0) {
    it = ft; ih = fh; iw = fw;
  } else {
    int s = topk[qlin * KK + k];
    int ti = s >> 6;                  // ct index (t0 == 0 always)
    int oi = (s >> 3) & 7, oj = s & 7;
    it = ti;
    ih = reflect(ci * 8 + oi - 4 + dh, HH);
    iw = reflect(cj * 8 + oj - 4 + dw, WW);
  }

  const float* b1 = v1 + (size_t)it * HWW * CC;
  float acc = 0.f;
#pragma unroll
  for (int pr = 0; pr < 7; ++pr) {
    int ry = reflect(ih + pr - 3, HH);
    const float* rowp = b1 + (size_t)ry * WW * CC + lane;
    float vals[7];
#pragma unroll
    for (int pc = 0; pc < 7; ++pc) {
      int rx = reflect(iw + pc - 3, WW);
      vals[pc] = rowp[(size_t)rx * CC];       // 7 independent loads in flight
    }
#pragma unroll
    for (int pc = 0; pc < 7; ++pc)
      acc = fmaf(qs[(pr * 7 + pc) * CC + lane], vals[pc], acc);
  }
#pragma unroll
  for (int off = 32; off > 0; off >>= 1)
    acc += __shfl_xor(acc, off, 64);
  if (lane == 0) {
    float* dout = out;                      // [0, QF*KK)
    float* iout = out + (size_t)QF * KK;    // [QF*KK, QF*KK*4)
    dout[(size_t)f * KK + k] = acc;
    float* ip = iout + ((size_t)f * KK + k) * 3;
    ip[0] = (float)it;
    ip[1] = (float)ih;
    ip[2] = (float)iw;
  }
}

// ---------------------------------------------------------------------------
extern "C" void kernel_launch(void* const* d_in, const int* in_sizes, int n_in,
                              void* d_out, int out_size, void* d_ws,
                              size_t ws_size, hipStream_t stream) {
  const float* vid0 = (const float*)d_in[0];
  const float* vid1 = (const float*)d_in[1];
  // d_in[2] = flows: unused by the reference.
  float* out = (float*)d_out;

  // Workspace layout:
  //   topk  : QC*KK int32 = 48 KB
  //   v0t   : TT*HH*WW*CC fp32 = 28.3 MB
  //   v1t   : 28.3 MB
  char* ws = (char*)d_ws;
  int* topk = (int*)ws;
  size_t off = (size_t)QC * KK * sizeof(int);
  off = (off + 255) & ~(size_t)255;
  float* v0t = (float*)(ws + off);
  size_t vbytes = (size_t)TT * HWW * CC * sizeof(float);
  float* v1t = (float*)(ws + off + vbytes);

  transpose_tchw_thwc<<<dim3(TT * HH * (WW / 64), 2), 256, 0, stream>>>(
      vid0, vid1, v0t, v1t);
  coarse_fma_kernel<<<QC, 256, 0, stream>>>(v0t, v1t, topk);
  refine_kernel<<<QF, 448, 0, stream>>>(v0t, v1t, topk, out);
}